// Round 1
// baseline (2881.186 us; speedup 1.0000x reference)
//
#include <hip/hip_runtime.h>
#include <math.h>

// Problem constants (fixed by setup_inputs)
constexpr int D  = 64;
constexpr int T  = 200;
constexpr int H0 = 80;
constexpr int H1 = 40;
constexpr int BLOCK = 256;
constexpr float NEG_INF_V = -4294967295.0f;

__global__ __launch_bounds__(BLOCK) void attn_kernel(
    const float* __restrict__ q, const float* __restrict__ k,
    const float* __restrict__ v, const float* __restrict__ W0,
    const float* __restrict__ b0, const float* __restrict__ a0,
    const float* __restrict__ W1, const float* __restrict__ b1,
    const float* __restrict__ a1, const float* __restrict__ Wo,
    const float* __restrict__ bo, const int* __restrict__ mask,
    float* __restrict__ out)
{
    __shared__ float s_q[D];
    __shared__ __align__(16) float s_weff[D][H0];   // folded layer-1 weights (per-batch)
    __shared__ float s_biasq[H0];
    __shared__ float s_a0[H0];
    __shared__ __align__(16) float s_W1[H0][H1];
    __shared__ float s_b1[H1];
    __shared__ float s_a1[H1];
    __shared__ float s_Wo[H1];
    __shared__ float s_red[BLOCK];
    __shared__ float s_w[BLOCK];
    __shared__ float s_part[4][D];

    const int tid = threadIdx.x;
    const int b   = blockIdx.x;

    // ---- Phase A: per-batch weight folding into LDS ----
    if (tid < D) s_q[tid] = q[(size_t)b * D + tid];
    for (int i = tid; i < H0 * H1; i += BLOCK) s_W1[i / H1][i % H1] = W1[i];
    if (tid < H1) { s_b1[tid] = b1[tid]; s_a1[tid] = a1[tid]; s_Wo[tid] = Wo[tid]; }
    if (tid < H0) s_a0[tid] = a0[tid];
    __syncthreads();

    for (int i = tid; i < D * H0; i += BLOCK) {
        int d = i / H0, h = i - d * H0;
        s_weff[d][h] = W0[(64 + d) * H0 + h] - W0[(128 + d) * H0 + h]
                     + s_q[d] * W0[(192 + d) * H0 + h];
    }
    if (tid < H0) {
        float acc = b0[tid];
        for (int d = 0; d < D; ++d)
            acc += s_q[d] * (W0[d * H0 + tid] + W0[(128 + d) * H0 + tid]);
        s_biasq[tid] = acc;
    }
    __syncthreads();

    // ---- Phase B: per-t MLP (thread t = tid), logits ----
    float logit;
    if (tid < T) {
        const float4* kp4 = (const float4*)(k + ((size_t)b * T + tid) * D);
        float4 kr[16];
        #pragma unroll
        for (int i = 0; i < 16; ++i) kr[i] = kp4[i];

        float h1acc[H1];
        #pragma unroll
        for (int g = 0; g < H1; ++g) h1acc[g] = 0.0f;

        #pragma unroll 1   // keep body (~9KB) inside icache
        for (int hb = 0; hb < H0; hb += 8) {
            float acc[8];
            #pragma unroll
            for (int j = 0; j < 8; ++j) acc[j] = s_biasq[hb + j];
            #pragma unroll
            for (int d4 = 0; d4 < 16; ++d4) {
                float4 kd = kr[d4];
                #pragma unroll
                for (int dd = 0; dd < 4; ++dd) {
                    const float kv = (dd == 0) ? kd.x : (dd == 1) ? kd.y
                                   : (dd == 2) ? kd.z : kd.w;
                    const float* wr = &s_weff[d4 * 4 + dd][0];
                    float4 wa = *(const float4*)(wr + hb);
                    float4 wb = *(const float4*)(wr + hb + 4);
                    acc[0] = fmaf(kv, wa.x, acc[0]);
                    acc[1] = fmaf(kv, wa.y, acc[1]);
                    acc[2] = fmaf(kv, wa.z, acc[2]);
                    acc[3] = fmaf(kv, wa.w, acc[3]);
                    acc[4] = fmaf(kv, wb.x, acc[4]);
                    acc[5] = fmaf(kv, wb.y, acc[5]);
                    acc[6] = fmaf(kv, wb.z, acc[6]);
                    acc[7] = fmaf(kv, wb.w, acc[7]);
                }
            }
            // PReLU + layer-2 accumulation on the fly (keeps h0 out of regs)
            #pragma unroll
            for (int j = 0; j < 8; ++j) {
                float x = acc[j];
                float h0v = (x >= 0.0f) ? x : s_a0[hb + j] * x;
                const float* w1r = &s_W1[hb + j][0];
                #pragma unroll
                for (int g4 = 0; g4 < H1; g4 += 4) {
                    float4 w = *(const float4*)(w1r + g4);
                    h1acc[g4 + 0] = fmaf(h0v, w.x, h1acc[g4 + 0]);
                    h1acc[g4 + 1] = fmaf(h0v, w.y, h1acc[g4 + 1]);
                    h1acc[g4 + 2] = fmaf(h0v, w.z, h1acc[g4 + 2]);
                    h1acc[g4 + 3] = fmaf(h0v, w.w, h1acc[g4 + 3]);
                }
            }
        }
        float lg = bo[0];
        #pragma unroll
        for (int g = 0; g < H1; ++g) {
            float x = h1acc[g] + s_b1[g];
            float h1v = (x >= 0.0f) ? x : s_a1[g] * x;
            lg = fmaf(h1v, s_Wo[g], lg);
        }
        logit = (mask[(size_t)b * T + tid] == 0) ? NEG_INF_V : lg;
    } else {
        logit = -INFINITY;   // pads contribute exp()=0 even in all-masked rows
    }

    // ---- Softmax over the block (T=200 real + 56 pad lanes) ----
    s_red[tid] = logit;
    __syncthreads();
    for (int s = BLOCK / 2; s > 0; s >>= 1) {
        if (tid < s) s_red[tid] = fmaxf(s_red[tid], s_red[tid + s]);
        __syncthreads();
    }
    const float m = s_red[0];
    __syncthreads();
    const float e = expf(logit - m);
    s_w[tid]   = e;
    s_red[tid] = e;
    __syncthreads();
    for (int s = BLOCK / 2; s > 0; s >>= 1) {
        if (tid < s) s_red[tid] += s_red[tid + s];
        __syncthreads();
    }
    const float inv = 1.0f / s_red[0];

    // ---- Phase C: out[b,d] = sum_t w_t * v[b,t,d], coalesced in d ----
    const int d = tid & (D - 1);
    const int c = tid >> 6;            // 0..3 chunks of T/4
    constexpr int TC = T / 4;          // 50
    float acc = 0.0f;
    const float* vp = v + ((size_t)b * T + c * TC) * D + d;
    for (int t = 0; t < TC; ++t)
        acc = fmaf(s_w[c * TC + t], vp[t * D], acc);
    s_part[c][d] = acc;
    __syncthreads();
    if (tid < D) {
        float r = (s_part[0][tid] + s_part[1][tid] + s_part[2][tid] + s_part[3][tid]) * inv;
        out[(size_t)b * D + tid] = r;
    }
}

extern "C" void kernel_launch(void* const* d_in, const int* in_sizes, int n_in,
                              void* d_out, int out_size, void* d_ws, size_t ws_size,
                              hipStream_t stream) {
    const float* q  = (const float*)d_in[0];
    const float* k  = (const float*)d_in[1];
    const float* v  = (const float*)d_in[2];
    const float* W0 = (const float*)d_in[3];
    const float* b0 = (const float*)d_in[4];
    const float* a0 = (const float*)d_in[5];
    const float* W1 = (const float*)d_in[6];
    const float* b1 = (const float*)d_in[7];
    const float* a1 = (const float*)d_in[8];
    const float* Wo = (const float*)d_in[9];
    const float* bo = (const float*)d_in[10];
    const int*  mask = (const int*)d_in[11];
    float* out = (float*)d_out;

    const int B = in_sizes[0] / D;     // 2048
    attn_kernel<<<dim3(B), dim3(BLOCK), 0, stream>>>(
        q, k, v, W0, b0, a0, W1, b1, a1, Wo, bo, mask, out);
}

// Round 2
// 473.273 us; speedup vs baseline: 6.0878x; 6.0878x over previous
//
#include <hip/hip_runtime.h>
#include <math.h>

constexpr int D  = 64;
constexpr int T  = 200;
constexpr int H0 = 80;
constexpr int H1 = 40;
constexpr int BLOCK = 256;
constexpr float NEG_INF_V = -4294967295.0f;

typedef float f8 __attribute__((ext_vector_type(8)));

// ---------------- Pre-kernel: fold per-batch layer-1 weights ----------------
// FOLDED=1: weff[b][d][h] = W0[64+d][h] - W0[128+d][h] + q_d*W0[192+d][h]  (42 MB)
// FOLDED=0: wbc[d][h]     = W0[64+d][h] - W0[128+d][h]                    (20 KB, b==0 only)
// Both: biasq[b][h] = b0[h] + sum_d q_d*(W0[d][h] + W0[128+d][h])
template<int FOLDED>
__global__ __launch_bounds__(256) void fold_k(
    const float* __restrict__ q, const float* __restrict__ W0,
    const float* __restrict__ b0, float* __restrict__ wout,
    float* __restrict__ biasq)
{
    const int b = blockIdx.x, tid = threadIdx.x;
    const float* qb = q + (size_t)b * D;
    if (FOLDED) {
        float* wb = wout + (size_t)b * D * H0;
        for (int i = tid; i < D * H0; i += 256) {
            int d = i / H0;
            wb[i] = W0[64 * H0 + i] - W0[128 * H0 + i] + qb[d] * W0[192 * H0 + i];
        }
    } else if (b == 0) {
        for (int i = tid; i < D * H0; i += 256)
            wout[i] = W0[64 * H0 + i] - W0[128 * H0 + i];
    }
    if (tid < H0) {
        float acc = b0[tid];
        for (int d = 0; d < D; ++d)
            acc = fmaf(qb[d], W0[d * H0 + tid] + W0[(128 + d) * H0 + tid], acc);
        biasq[(size_t)b * H0 + tid] = acc;
    }
}

// ---------------- Main kernel ----------------
// Weights come in via wave-uniform float8 loads (scalar path, no LDS, no VGPR cost).
template<int FOLDED>
__global__ __launch_bounds__(BLOCK) void attn_main(
    const float* __restrict__ k, const float* __restrict__ v,
    const float* __restrict__ q,
    const float* __restrict__ wA,      // FOLDED ? weff : wbc
    const float* __restrict__ wB,      // q*k weight rows = W0 + 192*H0 (only !FOLDED)
    const float* __restrict__ biasq,
    const float* __restrict__ a0, const float* __restrict__ W1,
    const float* __restrict__ b1, const float* __restrict__ a1,
    const float* __restrict__ Wo, const float* __restrict__ bo,
    const int* __restrict__ mask, float* __restrict__ out)
{
    __shared__ float s_w[BLOCK];
    __shared__ float s_red[BLOCK];
    __shared__ float s_part[4][D];

    const int tid = threadIdx.x;
    const int b   = blockIdx.x;

    const float* wAb = FOLDED ? wA + (size_t)b * (D * H0) : wA;
    const float* bq  = biasq + (size_t)b * H0;

    float logit;
    if (tid < T) {
        const float4* kp4 = (const float4*)(k + ((size_t)b * T + tid) * D);
        float4 kr[16];
        #pragma unroll
        for (int i = 0; i < 16; ++i) kr[i] = kp4[i];

        float h1acc[H1];
        #pragma unroll
        for (int g = 0; g < H1; ++g) h1acc[g] = 0.0f;

        #pragma unroll 1
        for (int hbi = 0; hbi < 10; ++hbi) {
            const int hb = hbi * 8;
            f8 bqv = *(const f8*)(bq + hb);
            float acc[8];
            #pragma unroll
            for (int j = 0; j < 8; ++j) acc[j] = bqv[j];

            #pragma unroll 2
            for (int d4 = 0; d4 < 16; ++d4) {
                const float4 kv = kr[d4];
                float4 qv;
                if (!FOLDED) qv = *(const float4*)(q + (size_t)b * D + d4 * 4);
                #pragma unroll
                for (int dd = 0; dd < 4; ++dd) {
                    const int d = d4 * 4 + dd;
                    const float kd = (dd == 0) ? kv.x : (dd == 1) ? kv.y
                                   : (dd == 2) ? kv.z : kv.w;
                    f8 wa = *(const f8*)(wAb + d * H0 + hb);
                    #pragma unroll
                    for (int j = 0; j < 8; ++j) acc[j] = fmaf(kd, wa[j], acc[j]);
                    if (!FOLDED) {
                        const float qd = (dd == 0) ? qv.x : (dd == 1) ? qv.y
                                       : (dd == 2) ? qv.z : qv.w;
                        const float pd = kd * qd;
                        f8 wd = *(const f8*)(wB + d * H0 + hb);
                        #pragma unroll
                        for (int j = 0; j < 8; ++j) acc[j] = fmaf(pd, wd[j], acc[j]);
                    }
                }
            }

            // PReLU + layer-2 accumulation (W1 rows via uniform loads)
            f8 al = *(const f8*)(a0 + hb);
            #pragma unroll
            for (int j = 0; j < 8; ++j) {
                const float x = acc[j];
                const float h0v = (x >= 0.0f) ? x : al[j] * x;
                const float* w1r = W1 + (hb + j) * H1;
                #pragma unroll
                for (int g8 = 0; g8 < 5; ++g8) {
                    f8 w = *(const f8*)(w1r + g8 * 8);
                    #pragma unroll
                    for (int u = 0; u < 8; ++u)
                        h1acc[g8 * 8 + u] = fmaf(h0v, w[u], h1acc[g8 * 8 + u]);
                }
            }
        }

        float lg = bo[0];
        #pragma unroll
        for (int g8 = 0; g8 < 5; ++g8) {
            f8 bb = *(const f8*)(b1 + g8 * 8);
            f8 aa = *(const f8*)(a1 + g8 * 8);
            f8 ww = *(const f8*)(Wo + g8 * 8);
            #pragma unroll
            for (int u = 0; u < 8; ++u) {
                const float x = h1acc[g8 * 8 + u] + bb[u];
                const float hv = (x >= 0.0f) ? x : aa[u] * x;
                lg = fmaf(hv, ww[u], lg);
            }
        }
        logit = (mask[(size_t)b * T + tid] == 0) ? NEG_INF_V : lg;
    } else {
        logit = -INFINITY;   // pads: exp() = 0 even in all-masked rows
    }

    // ---- Softmax over the block ----
    s_red[tid] = logit;
    __syncthreads();
    for (int s = BLOCK / 2; s > 0; s >>= 1) {
        if (tid < s) s_red[tid] = fmaxf(s_red[tid], s_red[tid + s]);
        __syncthreads();
    }
    const float m = s_red[0];
    __syncthreads();
    const float e = expf(logit - m);
    s_w[tid]   = e;
    s_red[tid] = e;
    __syncthreads();
    for (int s = BLOCK / 2; s > 0; s >>= 1) {
        if (tid < s) s_red[tid] += s_red[tid + s];
        __syncthreads();
    }
    const float inv = 1.0f / s_red[0];

    // ---- out[b,d] = sum_t w_t * v[b,t,d] ----
    const int d = tid & (D - 1);
    const int c = tid >> 6;
    constexpr int TC = T / 4;
    float acc = 0.0f;
    const float* vp = v + ((size_t)b * T + c * TC) * D + d;
    for (int t = 0; t < TC; ++t)
        acc = fmaf(s_w[c * TC + t], vp[t * D], acc);
    s_part[c][d] = acc;
    __syncthreads();
    if (tid < D) {
        float r = (s_part[0][tid] + s_part[1][tid] + s_part[2][tid] + s_part[3][tid]) * inv;
        out[(size_t)b * D + tid] = r;
    }
}

extern "C" void kernel_launch(void* const* d_in, const int* in_sizes, int n_in,
                              void* d_out, int out_size, void* d_ws, size_t ws_size,
                              hipStream_t stream) {
    const float* q  = (const float*)d_in[0];
    const float* k  = (const float*)d_in[1];
    const float* v  = (const float*)d_in[2];
    const float* W0 = (const float*)d_in[3];
    const float* b0 = (const float*)d_in[4];
    const float* a0 = (const float*)d_in[5];
    const float* W1 = (const float*)d_in[6];
    const float* b1 = (const float*)d_in[7];
    const float* a1 = (const float*)d_in[8];
    const float* Wo = (const float*)d_in[9];
    const float* bo = (const float*)d_in[10];
    const int*  mask = (const int*)d_in[11];
    float* out = (float*)d_out;
    float* ws  = (float*)d_ws;

    const int B = in_sizes[0] / D;            // 2048
    const float* w0d = W0 + 192 * H0;         // q*k weight rows

    const size_t need_fold = (size_t)B * D * H0 * 4 + (size_t)B * H0 * 4;
    if (ws_size >= need_fold) {
        float* weff  = ws;
        float* biasq = ws + (size_t)B * D * H0;
        fold_k<1><<<dim3(B), dim3(256), 0, stream>>>(q, W0, b0, weff, biasq);
        attn_main<1><<<dim3(B), dim3(BLOCK), 0, stream>>>(
            k, v, q, weff, w0d, biasq, a0, W1, b1, a1, Wo, bo, mask, out);
    } else {
        float* wbc   = ws;                    // [64][80]
        float* biasq = ws + D * H0;
        fold_k<0><<<dim3(B), dim3(256), 0, stream>>>(q, W0, b0, wbc, biasq);
        attn_main<0><<<dim3(B), dim3(BLOCK), 0, stream>>>(
            k, v, q, wbc, w0d, biasq, a0, W1, b1, a1, Wo, bo, mask, out);
    }
}